// Round 2
// baseline (402.628 us; speedup 1.0000x reference)
//
#include <hip/hip_runtime.h>
#include <hip/hip_bf16.h>
#include <cstdint>

typedef __bf16 bf16;
typedef __bf16 bf16x8 __attribute__((ext_vector_type(8)));
typedef __bf16 bf16x4 __attribute__((ext_vector_type(4)));
typedef float f32x4 __attribute__((ext_vector_type(4)));

__device__ __forceinline__ void gld_lds16(const void* g, void* l) {
  __builtin_amdgcn_global_load_lds((const __attribute__((address_space(1))) void*)g,
                                   (__attribute__((address_space(3))) void*)l, 16, 0, 0);
}

enum { BIAS_NONE = 0, BIAS_COL = 1, BIAS_ROW = 2 };
enum { OUT_BF16 = 0, OUT_F32_RESID = 1 };

// C[M,N] = A[M,K] * B^T (B stored [N,K], K contiguous) ; 128x128 tile, 4 waves.
template<int BIAS_MODE, int OUT_MODE>
__global__ __launch_bounds__(256)
void gemm_bt(const bf16* __restrict__ A, long sA, int lda,
             const bf16* __restrict__ Bm, long sB, int ldb,
             void* __restrict__ Cv, long sC, int ldc,
             const float* __restrict__ bias, float bscale,
             const float* __restrict__ resid, long sR,
             int K, float scale)
{
  const int bm = blockIdx.x, bn = blockIdx.y, bz = blockIdx.z;
  const char* Ab = (const char*)(A + (long)bz * sA);
  const char* Bb = (const char*)(Bm + (long)bz * sB);
  const int tid = threadIdx.x;
  const int wave = tid >> 6, lane = tid & 63;
  const int wr = wave >> 1, wc = wave & 1;

  __shared__ __attribute__((aligned(128))) char lds[32768];
  char* ldsA = lds;
  char* ldsB = lds + 16384;

  uint32_t aoff[4], boff[4];
#pragma unroll
  for (int i = 0; i < 4; ++i) {
    uint32_t ra = (uint32_t)(wr * 64 + i * 16 + (lane & 15));
    uint32_t la = ra * 128u + (uint32_t)((lane >> 4) << 4);
    aoff[i] = la ^ ((la >> 3) & 0x70u);
    uint32_t rb = (uint32_t)(wc * 64 + i * 16 + (lane & 15));
    uint32_t lb = rb * 128u + (uint32_t)((lane >> 4) << 4);
    boff[i] = lb ^ ((lb >> 3) & 0x70u);
  }

  uint32_t srow[4], sinb[4];
#pragma unroll
  for (int t = 0; t < 4; ++t) {
    uint32_t paddr = (uint32_t)(((wave * 4 + t) * 64 + lane) * 16);
    uint32_t laddr = paddr ^ ((paddr >> 3) & 0x70u);
    srow[t] = laddr >> 7;
    sinb[t] = laddr & 127u;
  }

  const long ldab = (long)lda * 2, ldbb = (long)ldb * 2;
  const long arow0 = (long)bm * 128, brow0 = (long)bn * 128;

  f32x4 acc[4][4] = {};

  const int nK = K >> 6;
  for (int kt = 0; kt < nK; ++kt) {
    const long k0b = (long)kt * 128;
#pragma unroll
    for (int t = 0; t < 4; ++t) {
      gld_lds16(Ab + (arow0 + srow[t]) * ldab + k0b + sinb[t],
                ldsA + (wave * 4 + t) * 1024);
      gld_lds16(Bb + (brow0 + srow[t]) * ldbb + k0b + sinb[t],
                ldsB + (wave * 4 + t) * 1024);
    }
    __syncthreads();
#pragma unroll
    for (int kk = 0; kk < 2; ++kk) {
      bf16x8 af[4], bfr[4];
#pragma unroll
      for (int i = 0; i < 4; ++i) {
        af[i]  = *(const bf16x8*)(ldsA + (aoff[i] ^ (kk << 6)));
        bfr[i] = *(const bf16x8*)(ldsB + (boff[i] ^ (kk << 6)));
      }
#pragma unroll
      for (int mi = 0; mi < 4; ++mi)
#pragma unroll
        for (int ni = 0; ni < 4; ++ni)
          acc[mi][ni] = __builtin_amdgcn_mfma_f32_16x16x32_bf16(af[mi], bfr[ni], acc[mi][ni], 0, 0, 0);
    }
    __syncthreads();
  }

  const int cl = lane & 15, rq = lane >> 4;
  const long row0 = (long)bm * 128 + wr * 64;
  const long col0 = (long)bn * 128 + wc * 64;

  if constexpr (OUT_MODE == OUT_BF16) {
    bf16* Co = (bf16*)Cv + (long)bz * sC;
#pragma unroll
    for (int mi = 0; mi < 4; ++mi) {
#pragma unroll
      for (int ni = 0; ni < 4; ++ni) {
        const long col = col0 + ni * 16 + cl;
        float bc = 0.f;
        if (BIAS_MODE == BIAS_COL) bc = bias[col] * bscale;
#pragma unroll
        for (int j = 0; j < 4; ++j) {
          const long row = row0 + mi * 16 + rq * 4 + j;
          float v = acc[mi][ni][j] * scale + bc;
          if (BIAS_MODE == BIAS_ROW) v += bias[row] * bscale;
          Co[row * ldc + col] = (bf16)v;
        }
      }
    }
  } else {
    float* Co = (float*)Cv + (long)bz * sC;
    const float* X = resid + (long)bz * sR;
#pragma unroll
    for (int mi = 0; mi < 4; ++mi) {
#pragma unroll
      for (int ni = 0; ni < 4; ++ni) {
        const long col = col0 + ni * 16 + cl;
#pragma unroll
        for (int j = 0; j < 4; ++j) {
          const long row = row0 + mi * 16 + rq * 4 + j;
          Co[row * ldc + col] = acc[mi][ni][j] + bias[row] * bscale + X[row * ldc + col];
        }
      }
    }
  }
}

// ---------------- fused flash attention ----------------
// 1 block per (batch, 64 Q-rows); 8 waves; Q in LDS [64][512]; KV 2x32KB dbuf;
// online softmax; O accumulated in regs (64 VGPR/lane).
#define FA_LDS_SIZE 149504

__global__ __launch_bounds__(512, 2)
void flash_attn(const bf16* __restrict__ Qg, const bf16* __restrict__ Kg,
                const bf16* __restrict__ Vg, bf16* __restrict__ Og)
{
  extern __shared__ char lds[];
  char* ldsQ = lds;                       // 65536: [64][512] bf16, swz ^((row&7)<<4)
  char* buf0 = lds + 65536;               // 32768
  char* buf1 = lds + 98304;               // 32768
  char* ldsP = lds + 131072;              // 16384: [64][128] bf16, swz ^((row&7)<<4)
  float* pred = (float*)(lds + 147456);   // [64][4] partial max / sum

  const int bid = blockIdx.x;
  const int b  = (bid & 7) >> 1;                  // 2 XCDs per batch (L2 locality)
  const int rb = ((bid >> 3) << 1) | (bid & 1);
  const int n0 = rb * 64;
  const int tid = threadIdx.x;
  const int wave = tid >> 6, lane = tid & 63;
  const int wr = wave >> 2, wc = wave & 3;
  const int lg = lane >> 4, l15 = lane & 15;

  const char* Qb = (const char*)(Qg + ((long)b * 4096 + n0) * 512);
  const char* Kb = (const char*)(Kg + (long)b * 4096 * 512);
  const char* Vb = (const char*)(Vg + (long)b * 512 * 4096);

  // staging descriptors (per-thread constants)
  uint32_t q_goff[8], k_goff[4], v_goff[4];
#pragma unroll
  for (int it = 0; it < 8; ++it) {
    uint32_t s = it * 512 + tid;
    uint32_t row = s >> 6, off = (s & 63) * 16;
    q_goff[it] = row * 1024 + (off ^ ((row & 7) << 4));
  }
#pragma unroll
  for (int it = 0; it < 4; ++it) {
    uint32_t s = it * 512 + tid;
    uint32_t row = s >> 4, off = (s & 15) * 16;
    k_goff[it] = row * 1024 + (off ^ ((row & 7) << 4));
  }
#pragma unroll
  for (int it = 0; it < 4; ++it) {
    uint32_t s = it * 512 + tid;
    uint32_t d = s >> 2, off = (s & 3) * 16;
    v_goff[it] = d * 8192 + (off ^ (((d >> 1) & 3) << 4));
  }
  const uint32_t dst0 = (uint32_t)tid * 16;

  // fragment base offsets
  uint32_t qb_[2], qs_[2], pb_[2], ps_[2], kb_[2], ks_[2], vb_[8], vs_[8];
#pragma unroll
  for (int mi = 0; mi < 2; ++mi) {
    uint32_t r = wr * 32 + mi * 16 + l15;
    qb_[mi] = r * 1024; qs_[mi] = (r & 7) << 4;
    pb_[mi] = r * 256;  ps_[mi] = (r & 7) << 4;
  }
#pragma unroll
  for (int ni = 0; ni < 2; ++ni) {
    uint32_t r = wc * 32 + ni * 16 + l15;
    kb_[ni] = r * 256; ks_[ni] = (r & 7) << 4;
  }
#pragma unroll
  for (int ni = 0; ni < 8; ++ni) {
    uint32_t d = wc * 128 + ni * 16 + l15;
    vb_[ni] = d * 64; vs_[ni] = ((d >> 1) & 3) << 4;
  }

  f32x4 acc_o[2][8] = {};
  f32x4 acc_s[2][2] = {};
  float m_run[2][4], l_run[2][4];
#pragma unroll
  for (int mi = 0; mi < 2; ++mi)
#pragma unroll
    for (int j = 0; j < 4; ++j) { m_run[mi][j] = -3.0e38f; l_run[mi][j] = 0.f; }

  auto stage_k = [&](char* buf, long kv0, int dc) {
    const char* src = Kb + kv0 * 1024 + dc * 256;
#pragma unroll
    for (int it = 0; it < 4; ++it)
      gld_lds16(src + k_goff[it], buf + it * 8192 + dst0);
  };
  auto stage_v = [&](char* buf, long kvcol) {
    const char* src = Vb + kvcol * 2;
#pragma unroll
    for (int it = 0; it < 4; ++it)
      gld_lds16(src + v_goff[it], buf + it * 8192 + dst0);
  };
  auto qk_phase = [&](const char* kb, int dc) {
#pragma unroll
    for (int kk = 0; kk < 4; ++kk) {
      bf16x8 a[2], bb[2];
#pragma unroll
      for (int mi = 0; mi < 2; ++mi)
        a[mi] = *(const bf16x8*)(ldsQ + qb_[mi] + ((uint32_t)(dc * 256 + kk * 64 + lg * 16) ^ qs_[mi]));
#pragma unroll
      for (int ni = 0; ni < 2; ++ni)
        bb[ni] = *(const bf16x8*)(kb + kb_[ni] + ((uint32_t)(kk * 64 + lg * 16) ^ ks_[ni]));
#pragma unroll
      for (int mi = 0; mi < 2; ++mi)
#pragma unroll
        for (int ni = 0; ni < 2; ++ni)
          acc_s[mi][ni] = __builtin_amdgcn_mfma_f32_16x16x32_bf16(a[mi], bb[ni], acc_s[mi][ni], 0, 0, 0);
    }
  };
  auto pv_phase = [&](const char* vbuf, int s) {
    bf16x8 a[2];
#pragma unroll
    for (int mi = 0; mi < 2; ++mi)
      a[mi] = *(const bf16x8*)(ldsP + pb_[mi] + ((uint32_t)(s * 64 + lg * 16) ^ ps_[mi]));
#pragma unroll
    for (int ni = 0; ni < 8; ++ni) {
      bf16x8 bb = *(const bf16x8*)(vbuf + vb_[ni] + ((uint32_t)(lg * 16) ^ vs_[ni]));
#pragma unroll
      for (int mi = 0; mi < 2; ++mi)
        acc_o[mi][ni] = __builtin_amdgcn_mfma_f32_16x16x32_bf16(a[mi], bb, acc_o[mi][ni], 0, 0, 0);
    }
  };

  // prologue: Q + first K chunk
#pragma unroll
  for (int it = 0; it < 8; ++it)
    gld_lds16(Qb + q_goff[it], ldsQ + it * 8192 + dst0);
  stage_k(buf0, 0, 0);
  __syncthreads();

  for (int t = 0; t < 32; ++t) {
    const long kv0 = (long)t * 128;
    stage_k(buf1, kv0, 1);  qk_phase(buf0, 0); __syncthreads();
    stage_k(buf0, kv0, 2);  qk_phase(buf1, 1); __syncthreads();
    stage_k(buf1, kv0, 3);  qk_phase(buf0, 2); __syncthreads();
    stage_v(buf0, kv0);     qk_phase(buf1, 3); __syncthreads();

    // sm1: cross-wave partial row max
    float tmx[2][4];
#pragma unroll
    for (int mi = 0; mi < 2; ++mi)
#pragma unroll
      for (int j = 0; j < 4; ++j) {
        float tv = fmaxf(acc_s[mi][0][j], acc_s[mi][1][j]);
#pragma unroll
        for (int d = 1; d < 16; d <<= 1) tv = fmaxf(tv, __shfl_xor(tv, d, 64));
        tmx[mi][j] = tv;
      }
    if (l15 == 0) {
#pragma unroll
      for (int mi = 0; mi < 2; ++mi)
#pragma unroll
        for (int j = 0; j < 4; ++j)
          pred[(wr * 32 + mi * 16 + lg * 4 + j) * 4 + wc] = tmx[mi][j];
    }
    __syncthreads();

    // sm2: combine, rescale O, P=exp(S-m), write P
#pragma unroll
    for (int mi = 0; mi < 2; ++mi)
#pragma unroll
      for (int j = 0; j < 4; ++j) {
        const int row = wr * 32 + mi * 16 + lg * 4 + j;
        float4 pm = *(const float4*)&pred[row * 4];
        float tm = fmaxf(fmaxf(pm.x, pm.y), fmaxf(pm.z, pm.w));
        float mnew = fmaxf(m_run[mi][j], tm);
        float alpha = __expf(m_run[mi][j] - mnew);
        m_run[mi][j] = mnew;
        l_run[mi][j] *= alpha;
#pragma unroll
        for (int ni = 0; ni < 8; ++ni) acc_o[mi][ni][j] *= alpha;
#pragma unroll
        for (int ni = 0; ni < 2; ++ni) {
          float p = __expf(acc_s[mi][ni][j] - mnew);
          l_run[mi][j] += p;
          const int col = wc * 32 + ni * 16 + l15;
          *(bf16*)(ldsP + row * 256 + (((uint32_t)(col * 2)) ^ ((row & 7) << 4))) = (bf16)p;
          acc_s[mi][ni][j] = 0.f;
        }
      }
    __syncthreads();

    stage_v(buf1, kv0 + 32);  pv_phase(buf0, 0); __syncthreads();
    stage_v(buf0, kv0 + 64);  pv_phase(buf1, 1); __syncthreads();
    stage_v(buf1, kv0 + 96);  pv_phase(buf0, 2); __syncthreads();
    if (t < 31) stage_k(buf0, kv0 + 128, 0);
    pv_phase(buf1, 3); __syncthreads();
  }

  // epilogue: reduce l across lanes+waves, write O
#pragma unroll
  for (int mi = 0; mi < 2; ++mi)
#pragma unroll
    for (int j = 0; j < 4; ++j) {
      float l = l_run[mi][j];
#pragma unroll
      for (int d = 1; d < 16; d <<= 1) l += __shfl_xor(l, d, 64);
      if (l15 == 0) pred[(wr * 32 + mi * 16 + lg * 4 + j) * 4 + wc] = l;
    }
  __syncthreads();
  bf16* Ob = Og + ((long)b * 4096 + n0) * 512;
#pragma unroll
  for (int mi = 0; mi < 2; ++mi)
#pragma unroll
    for (int j = 0; j < 4; ++j) {
      const int row = wr * 32 + mi * 16 + lg * 4 + j;
      float4 s4 = *(const float4*)&pred[row * 4];
      float r = 1.f / (s4.x + s4.y + s4.z + s4.w);
#pragma unroll
      for (int ni = 0; ni < 8; ++ni)
        Ob[(long)row * 512 + wc * 128 + ni * 16 + l15] = (bf16)(acc_o[mi][ni][j] * r);
    }
}

// ---------------- groupnorm / converts ----------------
__global__ __launch_bounds__(256)
void gn_stats(const float* __restrict__ x, float* __restrict__ stats)
{
  const int bg = blockIdx.x;
  const float4* px = (const float4*)(x + (long)bg * 65536);
  float s1 = 0.f, s2 = 0.f;
  for (int i = threadIdx.x; i < 16384; i += 256) {
    float4 f = px[i];
    s1 += f.x + f.y + f.z + f.w;
    s2 += f.x * f.x + f.y * f.y + f.z * f.z + f.w * f.w;
  }
#pragma unroll
  for (int d = 32; d > 0; d >>= 1) {
    s1 += __shfl_xor(s1, d, 64);
    s2 += __shfl_xor(s2, d, 64);
  }
  __shared__ float r1[4], r2[4];
  const int wave = threadIdx.x >> 6, lane = threadIdx.x & 63;
  if (lane == 0) { r1[wave] = s1; r2[wave] = s2; }
  __syncthreads();
  if (threadIdx.x == 0) {
    float t1 = r1[0] + r1[1] + r1[2] + r1[3];
    float t2 = r2[0] + r2[1] + r2[2] + r2[3];
    float mean = t1 * (1.f / 65536.f);
    float var  = t2 * (1.f / 65536.f) - mean * mean;
    stats[bg * 2]     = mean;
    stats[bg * 2 + 1] = rsqrtf(var + 1e-6f);
  }
}

__global__ __launch_bounds__(256)
void gn_apply(const float* __restrict__ x, const float* __restrict__ stats,
              const float* __restrict__ gamma, const float* __restrict__ beta,
              bf16* __restrict__ hn)
{
  const int b = blockIdx.y;
  const int n0 = blockIdx.x * 64;
  __shared__ __attribute__((aligned(16))) char lt[65536];
  const int tid = threadIdx.x;

  for (int i = 0; i < 32; ++i) {
    int f = i * 256 + tid;
    int c = f >> 4;
    int n4 = f & 15;
    float4 xv = *(const float4*)(x + (((long)b * 512 + c) * 4096) + n0 + n4 * 4);
    int g = c >> 4;
    float mean = stats[(b * 32 + g) * 2];
    float rstd = stats[(b * 32 + g) * 2 + 1];
    float ga = gamma[c], be = beta[c];
    float y[4];
    y[0] = (xv.x - mean) * rstd * ga + be;
    y[1] = (xv.y - mean) * rstd * ga + be;
    y[2] = (xv.z - mean) * rstd * ga + be;
    y[3] = (xv.w - mean) * rstd * ga + be;
    uint32_t cb = (uint32_t)(c * 2);
#pragma unroll
    for (int jj = 0; jj < 4; ++jj) {
      uint32_t nl = (uint32_t)(n4 * 4 + jj);
      uint32_t phys = nl * 1024u + (cb ^ (((nl >> 2) & 7u) << 4));
      *(bf16*)(lt + phys) = (bf16)y[jj];
    }
  }
  __syncthreads();
  for (int i = 0; i < 16; ++i) {
    int j = i * 256 + tid;
    uint32_t row = (uint32_t)(j >> 6);
    uint32_t m = (uint32_t)(j & 63);
    uint32_t phys = row * 1024u + ((m * 16u) ^ (((row >> 2) & 7u) << 4));
    uint4 val = *(const uint4*)(lt + phys);
    *(uint4*)((char*)(hn + ((long)b * 4096 + n0 + row) * 512) + m * 16) = val;
  }
}

__global__ __launch_bounds__(256)
void f32_to_bf16_k(const float* __restrict__ src, bf16* __restrict__ dst, int n4)
{
  int i = blockIdx.x * 256 + threadIdx.x;
  if (i < n4) {
    float4 f = ((const float4*)src)[i];
    bf16x4 o;
    o[0] = (bf16)f.x; o[1] = (bf16)f.y; o[2] = (bf16)f.z; o[3] = (bf16)f.w;
    ((bf16x4*)dst)[i] = o;
  }
}

extern "C" void kernel_launch(void* const* d_in, const int* in_sizes, int n_in,
                              void* d_out, int out_size, void* d_ws, size_t ws_size,
                              hipStream_t stream)
{
  const float* x     = (const float*)d_in[0];
  const float* gamma = (const float*)d_in[1];
  const float* beta  = (const float*)d_in[2];
  const float* wq = (const float*)d_in[3];
  const float* bq = (const float*)d_in[4];
  const float* wk = (const float*)d_in[5];
  const float* bk = (const float*)d_in[6];
  const float* wv = (const float*)d_in[7];
  const float* bv = (const float*)d_in[8];
  const float* wo = (const float*)d_in[9];
  const float* bo = (const float*)d_in[10];
  float* out = (float*)d_out;

  char* ws = (char*)d_ws;
  bf16* hn  = (bf16*)(ws + 0);          // [4][4096][512]
  bf16* q   = (bf16*)(ws + 16777216);   // [4][4096][512] (pre-scaled)
  bf16* k   = (bf16*)(ws + 33554432);   // [4][4096][512]
  bf16* v   = (bf16*)(ws + 50331648);   // [4][512][4096]
  bf16* O   = (bf16*)(ws + 67108864);   // [4][4096][512]
  bf16* wqb = (bf16*)(ws + 83886080);
  bf16* wkb = (bf16*)(ws + 84410368);
  bf16* wvb = (bf16*)(ws + 84934656);
  bf16* wob = (bf16*)(ws + 85458944);
  float* stats = (float*)(ws + 85983232);

  const long sBC = 2097152;
  const float scale = 0.044194173824159216f; // 512^-0.5

  hipFuncSetAttribute(reinterpret_cast<const void*>(flash_attn),
                      hipFuncAttributeMaxDynamicSharedMemorySize, FA_LDS_SIZE);

  f32_to_bf16_k<<<256, 256, 0, stream>>>(wq, wqb, 65536);
  f32_to_bf16_k<<<256, 256, 0, stream>>>(wk, wkb, 65536);
  f32_to_bf16_k<<<256, 256, 0, stream>>>(wv, wvb, 65536);
  f32_to_bf16_k<<<256, 256, 0, stream>>>(wo, wob, 65536);
  gn_stats<<<128, 256, 0, stream>>>(x, stats);
  gn_apply<<<dim3(64, 4), 256, 0, stream>>>(x, stats, gamma, beta, hn);

  // q (scale folded), k, v projections
  gemm_bt<BIAS_COL, OUT_BF16><<<dim3(32, 4, 4), 256, 0, stream>>>(
      hn, sBC, 512, wqb, 0, 512, q, sBC, 512, bq, scale, nullptr, 0, 512, scale);
  gemm_bt<BIAS_COL, OUT_BF16><<<dim3(32, 4, 4), 256, 0, stream>>>(
      hn, sBC, 512, wkb, 0, 512, k, sBC, 512, bk, 1.f, nullptr, 0, 512, 1.f);
  gemm_bt<BIAS_ROW, OUT_BF16><<<dim3(4, 32, 4), 256, 0, stream>>>(
      wvb, 0, 512, hn, sBC, 512, v, sBC, 4096, bv, 1.f, nullptr, 0, 512, 1.f);

  flash_attn<<<256, 512, FA_LDS_SIZE, stream>>>(q, k, v, O);

  // out[b,o,n] = wo[o,:] . O[b,n,:] + bo[o] + x[b,o,n]
  gemm_bt<BIAS_ROW, OUT_F32_RESID><<<dim3(4, 32, 4), 256, 0, stream>>>(
      wob, 0, 512, O, sBC, 512, out, sBC, 4096, bo, 1.f, x, sBC, 512, 1.f);
}

// Round 3
// 322.451 us; speedup vs baseline: 1.2486x; 1.2486x over previous
//
#include <hip/hip_runtime.h>
#include <hip/hip_bf16.h>
#include <cstdint>

typedef __bf16 bf16;
typedef __bf16 bf16x8 __attribute__((ext_vector_type(8)));
typedef __bf16 bf16x4 __attribute__((ext_vector_type(4)));
typedef float f32x4 __attribute__((ext_vector_type(4)));

__device__ __forceinline__ void gld_lds16(const void* g, void* l) {
  __builtin_amdgcn_global_load_lds((const __attribute__((address_space(1))) void*)g,
                                   (__attribute__((address_space(3))) void*)l, 16, 0, 0);
}
__device__ __forceinline__ void bar() { asm volatile("s_barrier" ::: "memory"); }
template<int N> __device__ __forceinline__ void vmwaitc() {
  asm volatile("s_waitcnt vmcnt(%0)" :: "i"(N) : "memory");
}

// ================= 8-phase 256-wide GEMM engine =================
// C[M,N] = A[M,K] * B^T (B stored [N,K], K contiguous), bf16 out.
// MI=8: 256x256 tile (waves 2x4, per-wave 128x64). MI=4: 256x128 (4x2, 64x64).
// BK=64. LDS: A 2x32KB dbuf + B 2x(BN*128) dbuf, XOR swizzle bits[6:4]^=row&7.
// Per K-tile 4 phases (mh,nh quadrants); counted vmcnt, raw barriers, setprio.
template<int MI>
__global__ __launch_bounds__(512, 2)
void gemm8p(const bf16* __restrict__ A, long sA, int lda,
            const bf16* __restrict__ Bm, long sB, int ldb,
            bf16* __restrict__ C, long sC, int ldc,
            int K, float scale)
{
  constexpr int WNW = MI / 2;            // wave cols (4 or 2)
  constexpr int BN = WNW * 64;           // 256 or 128
  constexpr int BLOADS = BN / 128;       // loads per B-half (2 or 1)
  constexpr int NQ0 = 4 + BLOADS;        // 6 / 5
  constexpr int NQ3 = 4 + 2 * BLOADS;    // 8 / 6
  constexpr int NQ3E = 2 + BLOADS;       // 4 / 3
  constexpr int HR = MI * 8;             // A-half stripe rows (64 / 32)
  constexpr int HRL = (MI == 8) ? 6 : 5;
  constexpr int ATILE = 32768;
  constexpr int BTILE = BN * 128;
  constexpr int MIH = MI / 2;

  extern __shared__ char lds[];
  char* ldsA = lds;                // 2 * ATILE
  char* ldsB = lds + 2 * ATILE;    // 2 * BTILE

  const int bm = blockIdx.x, bn = blockIdx.y, bz = blockIdx.z;
  const int tid = threadIdx.x, wave = tid >> 6, lane = tid & 63;
  const int wr = wave / WNW, wc = wave % WNW;
  const int lg = lane >> 4, l15 = lane & 15;
  const long ldab = (long)lda * 2, ldbb = (long)ldb * 2;
  const char* Ab = (const char*)(A + (long)bz * sA) + (long)bm * 256 * ldab;
  const char* Bb = (const char*)(Bm + (long)bz * sB) + (long)bn * BN * ldbb;
  const int T = K >> 6;

  // staging descriptors
  uint32_t aR0[2], aIn[2];
#pragma unroll
  for (int j = 0; j < 2; ++j) {
    uint32_t s = j * 512 + tid, r = s >> 3;
    aIn[j] = (s & 7) * 16;
    aR0[j] = (r >> HRL) * (MI * 16) + (r & (HR - 1));
  }
  uint32_t bR0[BLOADS], bIn[BLOADS];
#pragma unroll
  for (int j = 0; j < BLOADS; ++j) {
    uint32_t s = j * 512 + tid, r = s >> 3;
    bIn[j] = (s & 7) * 16;
    bR0[j] = (r >> 5) * 64 + (r & 31);
  }

  // fragment base offsets (bank-conflict-free by construction: 2-way max)
  const uint32_t swz = (uint32_t)(l15 & 7) << 4;
  uint32_t aBase[2][MIH], bBase[2][2];
#pragma unroll
  for (int mh = 0; mh < 2; ++mh)
#pragma unroll
    for (int mi2 = 0; mi2 < MIH; ++mi2) {
      uint32_t row = wr * (MI * 16) + mh * HR + mi2 * 16 + l15;
      aBase[mh][mi2] = row * 128 + ((uint32_t)(lg * 16) ^ swz);
    }
#pragma unroll
  for (int nh = 0; nh < 2; ++nh)
#pragma unroll
    for (int ni2 = 0; ni2 < 2; ++ni2) {
      uint32_t row = wc * 64 + nh * 32 + ni2 * 16 + l15;
      bBase[nh][ni2] = row * 128 + ((uint32_t)(lg * 16) ^ swz);
    }

  f32x4 acc[MI][4] = {};
  bf16x8 aF[MIH][2], bF[2][2];

  auto stageA = [&](int h, int tt) {
#pragma unroll
    for (int j = 0; j < 2; ++j) {
      uint32_t R = aR0[j] + (uint32_t)h * HR;
      gld_lds16(Ab + (long)R * ldab + (long)tt * 128 + (aIn[j] ^ ((aR0[j] & 7) << 4)),
                ldsA + (uint32_t)(tt & 1) * ATILE + R * 128 + aIn[j]);
    }
  };
  auto stageB = [&](int h, int tt) {
#pragma unroll
    for (int j = 0; j < BLOADS; ++j) {
      uint32_t R = bR0[j] + (uint32_t)h * 32;
      gld_lds16(Bb + (long)R * ldbb + (long)tt * 128 + (bIn[j] ^ ((bR0[j] & 7) << 4)),
                ldsB + (uint32_t)(tt & 1) * BTILE + R * 128 + bIn[j]);
    }
  };

  // prologue: tile0 fully + first halves of tile1
  stageA(0, 0); stageB(0, 0); stageA(1, 0); stageB(1, 0);
  if (T > 1) { stageA(0, 1); stageB(0, 1); }
  if (T > 1) vmwaitc<NQ3>(); else vmwaitc<0>();
  bar();

  for (int t = 0; t < T; ++t) {
    const uint32_t bufA = (uint32_t)(t & 1) * ATILE;
    const uint32_t bufB = (uint32_t)(t & 1) * BTILE;

#pragma unroll
    for (int q = 0; q < 4; ++q) {
      const int mh = q >> 1, nh = q & 1;
      if (nh == 0) {
#pragma unroll
        for (int mi2 = 0; mi2 < MIH; ++mi2)
#pragma unroll
          for (int kk = 0; kk < 2; ++kk)
            aF[mi2][kk] = *(const bf16x8*)(ldsA + ((bufA + aBase[mh][mi2]) ^ (uint32_t)(kk << 6)));
      }
#pragma unroll
      for (int ni2 = 0; ni2 < 2; ++ni2)
#pragma unroll
        for (int kk = 0; kk < 2; ++kk)
          bF[ni2][kk] = *(const bf16x8*)(ldsB + ((bufB + bBase[nh][ni2]) ^ (uint32_t)(kk << 6)));

      if (q == 0)      { if (t + 1 < T) stageA(1, t + 1); }
      else if (q == 1) { if (t + 1 < T) stageB(1, t + 1); }
      else if (q == 2) { if (t + 2 < T) stageA(0, t + 2); }
      else             { if (t + 2 < T) stageB(0, t + 2); }

      bar();
      __builtin_amdgcn_s_setprio(1);
#pragma unroll
      for (int mi2 = 0; mi2 < MIH; ++mi2)
#pragma unroll
        for (int ni2 = 0; ni2 < 2; ++ni2)
#pragma unroll
          for (int kk = 0; kk < 2; ++kk)
            acc[mh * MIH + mi2][nh * 2 + ni2] =
              __builtin_amdgcn_mfma_f32_16x16x32_bf16(aF[mi2][kk], bF[ni2][kk],
                                                      acc[mh * MIH + mi2][nh * 2 + ni2], 0, 0, 0);
      __builtin_amdgcn_s_setprio(0);

      if (q == 0) {
        if (t + 1 < T) vmwaitc<NQ0>(); else vmwaitc<0>();
      } else if (q == 3) {
        if (t + 1 < T) { if (t + 2 < T) vmwaitc<NQ3>(); else vmwaitc<NQ3E>(); }
      }
      bar();
    }
  }

  // epilogue
  bf16* Co = C + (long)bz * sC;
  const int cl = l15, rq = lg;
  const long row0 = (long)bm * 256 + wr * (MI * 16);
  const long col0 = (long)bn * BN + wc * 64;
#pragma unroll
  for (int mi = 0; mi < MI; ++mi)
#pragma unroll
    for (int ni = 0; ni < 4; ++ni) {
      const long col = col0 + ni * 16 + cl;
#pragma unroll
      for (int j = 0; j < 4; ++j) {
        const long row = row0 + mi * 16 + rq * 4 + j;
        Co[row * ldc + col] = (bf16)(acc[mi][ni][j] * scale);
      }
    }
}

enum { BIAS_NONE = 0, BIAS_COL = 1, BIAS_ROW = 2 };
enum { OUT_BF16 = 0, OUT_F32_RESID = 1 };

// 128x128-tile GEMM (proven r1) for projections / out-proj
template<int BIAS_MODE, int OUT_MODE>
__global__ __launch_bounds__(256)
void gemm_bt(const bf16* __restrict__ A, long sA, int lda,
             const bf16* __restrict__ Bm, long sB, int ldb,
             void* __restrict__ Cv, long sC, int ldc,
             const float* __restrict__ bias, float bscale,
             const float* __restrict__ resid, long sR,
             int K, float scale)
{
  const int bm = blockIdx.x, bn = blockIdx.y, bz = blockIdx.z;
  const char* Ab = (const char*)(A + (long)bz * sA);
  const char* Bb = (const char*)(Bm + (long)bz * sB);
  const int tid = threadIdx.x;
  const int wave = tid >> 6, lane = tid & 63;
  const int wr = wave >> 1, wc = wave & 1;

  __shared__ __attribute__((aligned(128))) char lds[32768];
  char* ldsA = lds;
  char* ldsB = lds + 16384;

  uint32_t aoff[4], boff[4];
#pragma unroll
  for (int i = 0; i < 4; ++i) {
    uint32_t ra = (uint32_t)(wr * 64 + i * 16 + (lane & 15));
    uint32_t la = ra * 128u + (uint32_t)((lane >> 4) << 4);
    aoff[i] = la ^ ((la >> 3) & 0x70u);
    uint32_t rb = (uint32_t)(wc * 64 + i * 16 + (lane & 15));
    uint32_t lb = rb * 128u + (uint32_t)((lane >> 4) << 4);
    boff[i] = lb ^ ((lb >> 3) & 0x70u);
  }
  uint32_t srow[4], sinb[4];
#pragma unroll
  for (int t = 0; t < 4; ++t) {
    uint32_t paddr = (uint32_t)(((wave * 4 + t) * 64 + lane) * 16);
    uint32_t laddr = paddr ^ ((paddr >> 3) & 0x70u);
    srow[t] = laddr >> 7;
    sinb[t] = laddr & 127u;
  }

  const long ldab = (long)lda * 2, ldbb = (long)ldb * 2;
  const long arow0 = (long)bm * 128, brow0 = (long)bn * 128;
  f32x4 acc[4][4] = {};
  const int nK = K >> 6;
  for (int kt = 0; kt < nK; ++kt) {
    const long k0b = (long)kt * 128;
#pragma unroll
    for (int t = 0; t < 4; ++t) {
      gld_lds16(Ab + (arow0 + srow[t]) * ldab + k0b + sinb[t], ldsA + (wave * 4 + t) * 1024);
      gld_lds16(Bb + (brow0 + srow[t]) * ldbb + k0b + sinb[t], ldsB + (wave * 4 + t) * 1024);
    }
    __syncthreads();
#pragma unroll
    for (int kk = 0; kk < 2; ++kk) {
      bf16x8 af[4], bfr[4];
#pragma unroll
      for (int i = 0; i < 4; ++i) {
        af[i]  = *(const bf16x8*)(ldsA + (aoff[i] ^ (kk << 6)));
        bfr[i] = *(const bf16x8*)(ldsB + (boff[i] ^ (kk << 6)));
      }
#pragma unroll
      for (int mi = 0; mi < 4; ++mi)
#pragma unroll
        for (int ni = 0; ni < 4; ++ni)
          acc[mi][ni] = __builtin_amdgcn_mfma_f32_16x16x32_bf16(af[mi], bfr[ni], acc[mi][ni], 0, 0, 0);
    }
    __syncthreads();
  }

  const int cl = lane & 15, rq = lane >> 4;
  const long row0 = (long)bm * 128 + wr * 64;
  const long col0 = (long)bn * 128 + wc * 64;
  if constexpr (OUT_MODE == OUT_BF16) {
    bf16* Co = (bf16*)Cv + (long)bz * sC;
#pragma unroll
    for (int mi = 0; mi < 4; ++mi)
#pragma unroll
      for (int ni = 0; ni < 4; ++ni) {
        const long col = col0 + ni * 16 + cl;
        float bc = 0.f;
        if (BIAS_MODE == BIAS_COL) bc = bias[col] * bscale;
#pragma unroll
        for (int j = 0; j < 4; ++j) {
          const long row = row0 + mi * 16 + rq * 4 + j;
          float v = acc[mi][ni][j] * scale + bc;
          if (BIAS_MODE == BIAS_ROW) v += bias[row] * bscale;
          Co[row * ldc + col] = (bf16)v;
        }
      }
  } else {
    float* Co = (float*)Cv + (long)bz * sC;
    const float* X = resid + (long)bz * sR;
#pragma unroll
    for (int mi = 0; mi < 4; ++mi)
#pragma unroll
      for (int ni = 0; ni < 4; ++ni) {
        const long col = col0 + ni * 16 + cl;
#pragma unroll
        for (int j = 0; j < 4; ++j) {
          const long row = row0 + mi * 16 + rq * 4 + j;
          Co[row * ldc + col] = acc[mi][ni][j] + bias[row] * bscale + X[row * ldc + col];
        }
      }
  }
}

// ---------------- groupnorm / converts / softmax ----------------
__global__ __launch_bounds__(256)
void gn_stats(const float* __restrict__ x, float* __restrict__ stats)
{
  const int bg = blockIdx.x;
  const float4* px = (const float4*)(x + (long)bg * 65536);
  float s1 = 0.f, s2 = 0.f;
  for (int i = threadIdx.x; i < 16384; i += 256) {
    float4 f = px[i];
    s1 += f.x + f.y + f.z + f.w;
    s2 += f.x * f.x + f.y * f.y + f.z * f.z + f.w * f.w;
  }
#pragma unroll
  for (int d = 32; d > 0; d >>= 1) {
    s1 += __shfl_xor(s1, d, 64);
    s2 += __shfl_xor(s2, d, 64);
  }
  __shared__ float r1[4], r2[4];
  const int wave = threadIdx.x >> 6, lane = threadIdx.x & 63;
  if (lane == 0) { r1[wave] = s1; r2[wave] = s2; }
  __syncthreads();
  if (threadIdx.x == 0) {
    float t1 = r1[0] + r1[1] + r1[2] + r1[3];
    float t2 = r2[0] + r2[1] + r2[2] + r2[3];
    float mean = t1 * (1.f / 65536.f);
    float var  = t2 * (1.f / 65536.f) - mean * mean;
    stats[bg * 2]     = mean;
    stats[bg * 2 + 1] = rsqrtf(var + 1e-6f);
  }
}

__global__ __launch_bounds__(256)
void gn_apply(const float* __restrict__ x, const float* __restrict__ stats,
              const float* __restrict__ gamma, const float* __restrict__ beta,
              bf16* __restrict__ hn)
{
  const int b = blockIdx.y;
  const int n0 = blockIdx.x * 64;
  __shared__ __attribute__((aligned(16))) char lt[65536];
  const int tid = threadIdx.x;
  for (int i = 0; i < 32; ++i) {
    int f = i * 256 + tid;
    int c = f >> 4;
    int n4 = f & 15;
    float4 xv = *(const float4*)(x + (((long)b * 512 + c) * 4096) + n0 + n4 * 4);
    int g = c >> 4;
    float mean = stats[(b * 32 + g) * 2];
    float rstd = stats[(b * 32 + g) * 2 + 1];
    float ga = gamma[c], be = beta[c];
    float y[4];
    y[0] = (xv.x - mean) * rstd * ga + be;
    y[1] = (xv.y - mean) * rstd * ga + be;
    y[2] = (xv.z - mean) * rstd * ga + be;
    y[3] = (xv.w - mean) * rstd * ga + be;
    uint32_t cb = (uint32_t)(c * 2);
#pragma unroll
    for (int jj = 0; jj < 4; ++jj) {
      uint32_t nl = (uint32_t)(n4 * 4 + jj);
      uint32_t phys = nl * 1024u + (cb ^ (((nl >> 2) & 7u) << 4));
      *(bf16*)(lt + phys) = (bf16)y[jj];
    }
  }
  __syncthreads();
  for (int i = 0; i < 16; ++i) {
    int j = i * 256 + tid;
    uint32_t row = (uint32_t)(j >> 6);
    uint32_t m = (uint32_t)(j & 63);
    uint32_t phys = row * 1024u + ((m * 16u) ^ (((row >> 2) & 7u) << 4));
    uint4 val = *(const uint4*)(lt + phys);
    *(uint4*)((char*)(hn + ((long)b * 4096 + n0 + row) * 512) + m * 16) = val;
  }
}

__global__ __launch_bounds__(256)
void f32_to_bf16_k(const float* __restrict__ src, bf16* __restrict__ dst, int n4)
{
  int i = blockIdx.x * 256 + threadIdx.x;
  if (i < n4) {
    float4 f = ((const float4*)src)[i];
    bf16x4 o;
    o[0] = (bf16)f.x; o[1] = (bf16)f.y; o[2] = (bf16)f.z; o[3] = (bf16)f.w;
    ((bf16x4*)dst)[i] = o;
  }
}

__global__ __launch_bounds__(256)
void softmax_rows(bf16* __restrict__ S)
{
  const long row = (long)blockIdx.x * 4 + (threadIdx.x >> 6);
  const int lane = threadIdx.x & 63;
  bf16* p = S + row * 4096;
  float v[64];
#pragma unroll
  for (int i = 0; i < 8; ++i) {
    bf16x8 c = *(const bf16x8*)(p + (i * 64 + lane) * 8);
#pragma unroll
    for (int j = 0; j < 8; ++j) v[i * 8 + j] = (float)c[j];
  }
  float m = -3.0e38f;
#pragma unroll
  for (int i = 0; i < 64; ++i) m = fmaxf(m, v[i]);
#pragma unroll
  for (int d = 32; d > 0; d >>= 1) m = fmaxf(m, __shfl_xor(m, d, 64));
  float s = 0.f;
#pragma unroll
  for (int i = 0; i < 64; ++i) { v[i] = __expf(v[i] - m); s += v[i]; }
#pragma unroll
  for (int d = 32; d > 0; d >>= 1) s += __shfl_xor(s, d, 64);
  const float r = 1.f / s;
#pragma unroll
  for (int i = 0; i < 8; ++i) {
    bf16x8 c;
#pragma unroll
    for (int j = 0; j < 8; ++j) c[j] = (bf16)(v[i * 8 + j] * r);
    *(bf16x8*)(p + (i * 64 + lane) * 8) = c;
  }
}

extern "C" void kernel_launch(void* const* d_in, const int* in_sizes, int n_in,
                              void* d_out, int out_size, void* d_ws, size_t ws_size,
                              hipStream_t stream)
{
  const float* x     = (const float*)d_in[0];
  const float* gamma = (const float*)d_in[1];
  const float* beta  = (const float*)d_in[2];
  const float* wq = (const float*)d_in[3];
  const float* bq = (const float*)d_in[4];
  const float* wk = (const float*)d_in[5];
  const float* bk = (const float*)d_in[6];
  const float* wv = (const float*)d_in[7];
  const float* bv = (const float*)d_in[8];
  const float* wo = (const float*)d_in[9];
  const float* bo = (const float*)d_in[10];
  float* out = (float*)d_out;

  char* ws = (char*)d_ws;
  bf16* hn  = (bf16*)(ws + 0);          // [4][4096][512]
  bf16* q   = (bf16*)(ws + 16777216);   // [4][4096][512] (pre-scaled by 512^-0.5)
  bf16* k   = (bf16*)(ws + 33554432);   // [4][4096][512]
  bf16* v   = (bf16*)(ws + 50331648);   // [4][512][4096]
  bf16* O   = (bf16*)(ws + 67108864);   // [4][4096][512]
  bf16* wqb = (bf16*)(ws + 83886080);
  bf16* wkb = (bf16*)(ws + 84410368);
  bf16* wvb = (bf16*)(ws + 84934656);
  bf16* wob = (bf16*)(ws + 85458944);
  float* stats = (float*)(ws + 85983232);
  bf16* S   = (bf16*)(ws + 85984256);   // tier1: [4][4096][4096]

  const long sBC = 2097152;
  const long sS1 = 16777216;
  const float scale = 0.044194173824159216f; // 512^-0.5

  const int LDS_S  = 131072; // gemm8p<8>: 2*32K A + 2*32K B
  const int LDS_PV = 98304;  // gemm8p<4>: 2*32K A + 2*16K B
  hipFuncSetAttribute(reinterpret_cast<const void*>(gemm8p<8>),
                      hipFuncAttributeMaxDynamicSharedMemorySize, LDS_S);
  hipFuncSetAttribute(reinterpret_cast<const void*>(gemm8p<4>),
                      hipFuncAttributeMaxDynamicSharedMemorySize, LDS_PV);

  f32_to_bf16_k<<<256, 256, 0, stream>>>(wq, wqb, 65536);
  f32_to_bf16_k<<<256, 256, 0, stream>>>(wk, wkb, 65536);
  f32_to_bf16_k<<<256, 256, 0, stream>>>(wv, wvb, 65536);
  f32_to_bf16_k<<<256, 256, 0, stream>>>(wo, wob, 65536);
  gn_stats<<<128, 256, 0, stream>>>(x, stats);
  gn_apply<<<dim3(64, 4), 256, 0, stream>>>(x, stats, gamma, beta, hn);

  // projections (q has softmax scale folded into weights+bias)
  gemm_bt<BIAS_COL, OUT_BF16><<<dim3(32, 4, 4), 256, 0, stream>>>(
      hn, sBC, 512, wqb, 0, 512, q, sBC, 512, bq, scale, nullptr, 0, 512, scale);
  gemm_bt<BIAS_COL, OUT_BF16><<<dim3(32, 4, 4), 256, 0, stream>>>(
      hn, sBC, 512, wkb, 0, 512, k, sBC, 512, bk, 1.f, nullptr, 0, 512, 1.f);
  gemm_bt<BIAS_ROW, OUT_BF16><<<dim3(4, 32, 4), 256, 0, stream>>>(
      wvb, 0, 512, hn, sBC, 512, v, sBC, 4096, bv, 1.f, nullptr, 0, 512, 1.f);

  const bool tier1 = ws_size >= (size_t)220201984;
  if (tier1) {
    // S = q . k^T  (scale already folded into q)
    gemm8p<8><<<dim3(16, 16, 4), 512, LDS_S, stream>>>(
        q, sBC, 512, k, sBC, 512, S, sS1, 4096, 512, 1.f);
    softmax_rows<<<4096, 256, 0, stream>>>(S);
    // O = P . v^T   (v stored [512][4096], K=n contiguous)
    gemm8p<4><<<dim3(16, 4, 4), 512, LDS_PV, stream>>>(
        S, sS1, 4096, v, sBC, 4096, O, sBC, 512, 4096, 1.f);
  } else {
    for (int b = 0; b < 4; ++b) {
      gemm8p<8><<<dim3(16, 16, 1), 512, LDS_S, stream>>>(
          q + b * sBC, 0, 512, k + b * sBC, 0, 512, S, 0, 4096, 512, 1.f);
      softmax_rows<<<1024, 256, 0, stream>>>(S);
      gemm8p<4><<<dim3(16, 4, 1), 512, LDS_PV, stream>>>(
          S, 0, 4096, v + b * sBC, 0, 4096, O + b * sBC, 0, 512, 4096, 1.f);
    }
  }

  // out[b,o,n] = wo[o,:] . O[b,n,:] + bo[o] + x[b,o,n]
  gemm_bt<BIAS_ROW, OUT_F32_RESID><<<dim3(4, 32, 4), 256, 0, stream>>>(
      wob, 0, 512, O, sBC, 512, out, sBC, 4096, bo, 1.f, x, sBC, 512, 1.f);
}